// Round 9
// baseline (446.375 us; speedup 1.0000x reference)
//
#include <hip/hip_runtime.h>

// ---------------------------------------------------------------------------
// TransformerBlock on MI355X (gfx950), round 9:
//  - GEMM K-loop: BK=32, 4 LDS buffers, depth-3 prefetch with counted
//    s_waitcnt vmcnt(3*LPT). Same 64KB LDS footprint (2 blocks/CU for
//    TM=128; 48KB -> 3 blocks/CU for TM=64). Cur-tile loads get ~3 compute
//    phases to land instead of 1 -> latency actually covered.
//  - LDS tile rows are 64B (4 x 16B units), XOR-swizzle unit^=(row>>1)&3
//    (<=2-way bank aliasing) applied at stage-source and read.
//  - everything else unchanged from round 8.
// ---------------------------------------------------------------------------

typedef unsigned short u16;
typedef __attribute__((ext_vector_type(8))) short bh8;   // 8 x bf16
typedef __attribute__((ext_vector_type(4))) float fv4;
typedef __attribute__((ext_vector_type(4))) unsigned uv4;
typedef __attribute__((ext_vector_type(2))) int iv2;

#define LOG2E 1.4426950408889634f
#define MAX_TILES 71

__device__ __forceinline__ float b2f(u16 u) {
  return __builtin_bit_cast(float, ((unsigned)u) << 16);
}
__device__ __forceinline__ u16 f2b(float f) {
  unsigned x = __builtin_bit_cast(unsigned, f);
  return (u16)((x + 0x7fffu + ((x >> 16) & 1u)) >> 16);  // RNE
}
__device__ __forceinline__ fv4 mfma16(bh8 a, bh8 b, fv4 c) {
  return __builtin_amdgcn_mfma_f32_16x16x32_bf16(a, b, c, 0, 0, 0);
}
__device__ __forceinline__ unsigned cvtpk(float lo, float hi) {
  unsigned r;
  asm("v_cvt_pk_bf16_f32 %0, %1, %2" : "=v"(r) : "v"(lo), "v"(hi));
  return r;
}

// Bijective XCD-chunk swizzle (m204): blocks resident on one XCD cover a
// contiguous chunk of logical (y,x) space -> A-tiles/weights fetched once.
__device__ __forceinline__ void xcd_swizzle(int& bx, int& by) {
  int gx = gridDim.x;
  int nwg = gx * gridDim.y;
  int flat = by * gx + bx;
  int q = nwg >> 3, r = nwg & 7;
  int xcd = flat & 7, idx = flat >> 3;
  int swz = (xcd < r ? xcd * (q + 1) : r * (q + 1) + (xcd - r) * q) + idx;
  by = swz / gx;
  bx = swz - by * gx;
}

#define GLD16(g, l)                                                        \
  __builtin_amdgcn_global_load_lds(                                        \
      (const __attribute__((address_space(1))) void*)(g),                  \
      (__attribute__((address_space(3))) void*)(l), 16, 0, 0)

// Read one MFMA fragment (16B) from a [rows][32] bf16 LDS tile (64B rows,
// 4 x 16B units) whose units are XOR-swizzled by (row>>1)&3.
__device__ __forceinline__ bh8 lds_frag32(const u16* base, int row, int g) {
  int off = (row << 5) + (((g ^ (row >> 1)) & 3) << 3);
  return *(const bh8*)(base + off);
}

// Read frag from old-style [rows][64] tile with (row&7) 16B-unit swizzle
// (used by attention only).
__device__ __forceinline__ bh8 lds_frag(const u16* base, int row, int b8) {
  int off = row * 128 + ((b8 * 16) ^ ((row & 7) << 4));
  return *(const bh8*)((const char*)base + off);
}

// ---------------------------------------------------------------------------
// Generic GEMM: C[M,N] = A[M,K] (bf16) @ B[N,K]^T (bf16), f32 accumulate.
// TM: A-tile rows (128 or 64). B-tile is always 128 cols.
// MODE 0: Cb = bf16(gemm)
// MODE 1: Cf = add1 + gemm
// MODE 6: compact-A grouped MoE (w2): lda via M; Cb = bf16(gemm + bias_e)
// MODE 7: interleaved silu (shared expert): Cb[.,N/2] = silu(g)*u
// MODE 8: gather-A grouped MoE w13, interleaved silu + biases:
//         Cb[.,N/2] = silu(g + b1[e]) * (u + b3[e])   (add1=b1, add2=b3)
// MODE 9: final: Cf = add1 + gemm + w0*eo[r0] + w1*eo[r1]
//         (Cb=eo read-only, tmeta=rowid[2T], bias=topk_w[2T])
// K-loop: BK=32, 4 buffers, depth-3 prefetch, counted vmcnt, raw barriers.
// ---------------------------------------------------------------------------
template <int MODE, int TM = 128>
__global__ __launch_bounds__(256) void gemm_bt(
    const u16* __restrict__ A, const u16* __restrict__ B, int M, int N, int K,
    u16* __restrict__ Cb, float* __restrict__ Cf,
    const float* __restrict__ add1, const float* __restrict__ add2,
    const float* __restrict__ bias, const int* __restrict__ tmeta,
    const int* __restrict__ etok) {
  constexpr int MR = TM / 32;   // M-frags per wave: 128->4, 64->2
  constexpr int AC = MR / 2;    // A-loads per thread per tile
  __shared__ u16 As[4][TM * 32];
  __shared__ u16 Bs[4][128 * 32];
  int bx = blockIdx.x, by = blockIdx.y;
  xcd_swizzle(bx, by);
  const int lane = threadIdx.x & 63;
  const int wid = threadIdx.x >> 6;
  const int wr = wid >> 1, wc = wid & 1;
  const int n0 = bx * 128;
  const int l15 = lane & 15;
  const int g4 = lane >> 4;
  const int rr = lane >> 2;                      // row-in-chunk 0..15
  const int usrc = (lane & 3) ^ ((rr >> 1) & 3); // pre-swizzled source unit
  const int ldA = (MODE == 6) ? M : K;

  int m0 = 0, e = 0, m0l = 0, cnt = 0, row0 = 0;
  const u16* Bp = B;
  if constexpr (MODE == 6 || MODE == 8) {
    int tile = by;
    if (tile >= tmeta[0]) return;
    e = tmeta[16 + tile * 4];
    m0l = tmeta[17 + tile * 4];
    cnt = tmeta[18 + tile * 4];
    row0 = tmeta[19 + tile * 4];
    Bp = B + (size_t)e * N * K;
  } else {
    m0 = by * TM;
  }

  const u16* ArowP[AC];
  const u16* BrowP[2];
#pragma unroll
  for (int i = 0; i < AC; ++i) {
    int row = (wid * AC + i) * 16 + rr;
    if constexpr (MODE == 8) {
      int li = m0l + row;
      li = li < cnt ? li : cnt - 1;
      int tok = etok[e * 4096 + li];
      ArowP[i] = A + (size_t)tok * ldA + usrc * 8;
    } else if constexpr (MODE == 6) {
      ArowP[i] = A + (size_t)(row0 + row) * ldA + usrc * 8;
    } else {
      ArowP[i] = A + (size_t)(m0 + row) * ldA + usrc * 8;
    }
  }
#pragma unroll
  for (int i = 0; i < 2; ++i)
    BrowP[i] = Bp + (size_t)(n0 + (wid * 2 + i) * 16 + rr) * K + usrc * 8;

  fv4 acc[MR][4] = {};
  const int nt = K >> 5;

  auto stage = [&](int tt) {
    const int buf = tt & 3;
    const int k0 = tt << 5;
#pragma unroll
    for (int i = 0; i < AC; ++i)
      GLD16(ArowP[i] + k0, &As[buf][(wid * AC + i) * 512]);
#pragma unroll
    for (int i = 0; i < 2; ++i)
      GLD16(BrowP[i] + k0, &Bs[buf][(wid * 2 + i) * 512]);
  };
  stage(0);
  stage(1);
  stage(2);

  for (int t = 0; t < nt; ++t) {
    const int cur = t & 3;
    if (t + 3 < nt) stage(t + 3);
    __builtin_amdgcn_sched_barrier(0);   // pin issue order vs waitcnt
    if (t + 3 < nt) {
      if constexpr (MR == 4)
        asm volatile("s_waitcnt vmcnt(12)" ::: "memory");
      else
        asm volatile("s_waitcnt vmcnt(9)" ::: "memory");
    } else if (t + 2 < nt) {
      if constexpr (MR == 4)
        asm volatile("s_waitcnt vmcnt(8)" ::: "memory");
      else
        asm volatile("s_waitcnt vmcnt(6)" ::: "memory");
    } else if (t + 1 < nt) {
      if constexpr (MR == 4)
        asm volatile("s_waitcnt vmcnt(4)" ::: "memory");
      else
        asm volatile("s_waitcnt vmcnt(3)" ::: "memory");
    } else {
      asm volatile("s_waitcnt vmcnt(0)" ::: "memory");
    }
    __builtin_amdgcn_s_barrier();        // buf[cur] visible to all waves
    __builtin_amdgcn_sched_barrier(0);   // pin ds_reads below barrier

    bh8 af[MR], bf[4];
#pragma unroll
    for (int mi = 0; mi < MR; ++mi)
      af[mi] = lds_frag32(As[cur], wr * (16 * MR) + mi * 16 + l15, g4);
#pragma unroll
    for (int ni = 0; ni < 4; ++ni)
      bf[ni] = lds_frag32(Bs[cur], wc * 64 + ni * 16 + l15, g4);
    __builtin_amdgcn_s_setprio(1);
#pragma unroll
    for (int mi = 0; mi < MR; ++mi)
#pragma unroll
      for (int ni = 0; ni < 4; ++ni)
        acc[mi][ni] = mfma16(af[mi], bf[ni], acc[mi][ni]);
    __builtin_amdgcn_s_setprio(0);
    __builtin_amdgcn_sched_barrier(0);   // pin reads above barrier
    __builtin_amdgcn_s_barrier();        // all waves done reading buf[cur]
    __builtin_amdgcn_sched_barrier(0);   // pin next stage below barrier
  }

  const int rbase = (MODE == 6 || MODE == 8) ? row0 : m0;
  const int r0b = rbase + wr * (16 * MR) + (lane >> 4) * 4;
  const int c0b = n0 + wc * 64 + (lane & 15);

  if constexpr (MODE == 7 || MODE == 8) {
    const int OUTN = N >> 1;
    const int colb = (n0 >> 1) + wc * 32;
    const float* bb1 = nullptr;
    const float* bb3 = nullptr;
    if constexpr (MODE == 8) {
      bb1 = add1 + (size_t)e * OUTN;
      bb3 = add2 + (size_t)e * OUTN;
    }
#pragma unroll
    for (int mi = 0; mi < MR; ++mi) {
#pragma unroll
      for (int ni = 0; ni < 2; ++ni) {
        int c = colb + ni * 16 + (lane & 15);
#pragma unroll
        for (int r = 0; r < 4; ++r) {
          int row = r0b + mi * 16 + r;
          float xg = acc[mi][ni][r];
          float yu = acc[mi][ni + 2][r];
          if constexpr (MODE == 8) {
            xg += bb1[c];
            yu += bb3[c];
          }
          float s = xg / (1.f + __expf(-xg));
          Cb[(size_t)row * OUTN + c] = f2b(s * yu);
        }
      }
    }
  } else if constexpr (MODE == 9) {
#pragma unroll
    for (int mi = 0; mi < MR; ++mi) {
#pragma unroll
      for (int r = 0; r < 4; ++r) {
        int row = r0b + mi * 16 + r;
        int g0 = tmeta[2 * row], g1 = tmeta[2 * row + 1];
        float w0 = bias[2 * row], w1 = bias[2 * row + 1];
        const u16* e0p = Cb + (size_t)g0 * 1024;
        const u16* e1p = Cb + (size_t)g1 * 1024;
#pragma unroll
        for (int ni = 0; ni < 4; ++ni) {
          int c = c0b + ni * 16;
          size_t idx = (size_t)row * N + c;
          Cf[idx] = add1[idx] + acc[mi][ni][r] + w0 * b2f(e0p[c]) +
                    w1 * b2f(e1p[c]);
        }
      }
    }
  } else {
    const float* bb = nullptr;
    if constexpr (MODE == 6) bb = bias + (size_t)e * N;
#pragma unroll
    for (int mi = 0; mi < MR; ++mi) {
#pragma unroll
      for (int ni = 0; ni < 4; ++ni) {
        int c = c0b + ni * 16;
#pragma unroll
        for (int r = 0; r < 4; ++r) {
          int row = r0b + mi * 16 + r;
          size_t idx = (size_t)row * N + c;
          float v = acc[mi][ni][r];
          if constexpr (MODE == 0) Cb[idx] = f2b(v);
          else if constexpr (MODE == 1) Cf[idx] = add1[idx] + v;
          else Cb[idx] = f2b(v + bb[c]);
        }
      }
    }
  }
}

// ---------------------------------------------------------------------------
// RMSNorm: f32 [T,1024] -> bf16 [T,1024], one block per token.
// ---------------------------------------------------------------------------
__global__ __launch_bounds__(256) void rmsnorm_bf16(
    const float* __restrict__ x, const float* __restrict__ w,
    u16* __restrict__ out) {
  int t = blockIdx.x;
  const float* xr = x + (size_t)t * 1024;
  fv4 v = *(const fv4*)(xr + threadIdx.x * 4);
  float ss = v[0] * v[0] + v[1] * v[1] + v[2] * v[2] + v[3] * v[3];
#pragma unroll
  for (int off = 1; off < 64; off <<= 1) ss += __shfl_xor(ss, off);
  __shared__ float red[4];
  int lane = threadIdx.x & 63, wid = threadIdx.x >> 6;
  if (lane == 0) red[wid] = ss;
  __syncthreads();
  float inv = rsqrtf((red[0] + red[1] + red[2] + red[3]) * (1.0f / 1024.f) + 1e-6f);
  u16* op = out + (size_t)t * 1024 + threadIdx.x * 4;
  const float* wp = w + threadIdx.x * 4;
#pragma unroll
  for (int i = 0; i < 4; ++i) op[i] = f2b(v[i] * inv * wp[i]);
}

// ---------------------------------------------------------------------------
// RoPE + repack from fused qkv [T,3072]:
//   q,k -> rotated [B,NH,S,64]; v -> vt [B,NH,64,S] (transposed AND column-
//   permuted per 64-block: physical group pg=4ks+g holds logical j
//   {16ks+4g+r, 16ks+32+4g+r}).  Grid: (S/64, B, NH/4).
// ---------------------------------------------------------------------------
__global__ __launch_bounds__(256) void rope_repack(
    const u16* __restrict__ qkv, const float* __restrict__ fc,
    const float* __restrict__ fs, u16* __restrict__ qr, u16* __restrict__ kr,
    u16* __restrict__ vt, int S) {
  __shared__ u16 tile[64][65];
  const int s0 = blockIdx.x * 64;
  const int b = blockIdx.y;
  const int h0 = blockIdx.z * 4;
#pragma unroll 4
  for (int it = 0; it < 32; ++it) {
    int idx = threadIdx.x + it * 256;
    int tl = idx >> 7, rem = idx & 127;
    int h = h0 + (rem >> 5), i = rem & 31;
    int s = s0 + tl;
    float c = fc[s * 32 + i], sn = fs[s * 32 + i];
    size_t src = ((size_t)(b * S + s)) * 3072 + h * 64 + 2 * i;
    size_t dst = ((size_t)((b * 16 + h) * S + s)) * 64 + 2 * i;
    float a0 = b2f(qkv[src]), a1 = b2f(qkv[src + 1]);
    qr[dst] = f2b(a0 * c - a1 * sn);
    qr[dst + 1] = f2b(a0 * sn + a1 * c);
    float b0 = b2f(qkv[src + 1024]), b1 = b2f(qkv[src + 1025]);
    kr[dst] = f2b(b0 * c - b1 * sn);
    kr[dst + 1] = f2b(b0 * sn + b1 * c);
  }
  for (int hh = 0; hh < 4; ++hh) {
    int h = h0 + hh;
    __syncthreads();
    for (int cc = threadIdx.x; cc < 512; cc += 256) {
      int tl = cc >> 3, d8 = cc & 7;
      bh8 val = *(const bh8*)(qkv + ((size_t)(b * S + s0 + tl)) * 3072 + 2048 +
                              h * 64 + d8 * 8);
#pragma unroll
      for (int j = 0; j < 8; ++j) tile[tl][d8 * 8 + j] = (u16)val[j];
    }
    __syncthreads();
    for (int cc = threadIdx.x; cc < 512; cc += 256) {
      int d = cc >> 3, pg = cc & 7;
      int sbase = 16 * (pg >> 2) + 4 * (pg & 3);
      bh8 o;
#pragma unroll
      for (int j = 0; j < 8; ++j)
        o[j] = (short)tile[sbase + (j & 3) + ((j >> 2) << 5)][d];
      *(bh8*)(vt + ((size_t)((b * 16 + h) * 64 + d)) * S + s0 + pg * 8) = o;
    }
  }
}

// ---------------------------------------------------------------------------
// Flash attention (causal), paired q-tiles, hoisted shared K/V frags,
// MFMA row-sum (l in C-layout), fma-folded scale, defer-max.
// Grid: (B*NH, nq/2). 4 waves x 16 q-rows, KVBLK=64, dbuf staging.
// ---------------------------------------------------------------------------
__global__ __launch_bounds__(256) void attn_fwd(
    const u16* __restrict__ qr, const u16* __restrict__ kr,
    const u16* __restrict__ vt, u16* __restrict__ ob, int S, int NHc) {
  __shared__ u16 Ks[2][64 * 64];
  __shared__ u16 Vs[2][64 * 64];   // V^T tile, column-permuted
  const int lane = threadIdx.x & 63;
  const int wid = threadIdx.x >> 6;
  const int g = lane >> 4;
  const int l15 = lane & 15;
  const int bh = blockIdx.x;
  const int ia = blockIdx.y;
  const int nq = S / 64;
  const int qa0 = ia * 64;                 // light q-tile
  const int qb0 = (nq - 1 - ia) * 64;      // heavy q-tile
  const int b = bh / NHc, h = bh % NHc;
  const u16* qbase = qr + (size_t)bh * S * 64;
  const u16* kb = kr + (size_t)bh * S * 64;
  const u16* vb = vt + (size_t)bh * 64 * S;
  const float SC = 0.015625f * LOG2E;  // both ref scales, log2 domain
  const int rr = lane >> 3;
  const int b8s = (lane & 7) ^ rr;

  bh8 ONES;
#pragma unroll
  for (int j = 0; j < 8; ++j) ONES[j] = (short)0x3f80;  // bf16 1.0

  bh8 qfA[2], qfB[2];
  {
    const u16* qp = qbase + (size_t)(qa0 + wid * 16 + l15) * 64 + g * 8;
    qfA[0] = *(const bh8*)qp;
    qfA[1] = *(const bh8*)(qp + 32);
    qp = qbase + (size_t)(qb0 + wid * 16 + l15) * 64 + g * 8;
    qfB[0] = *(const bh8*)qp;
    qfB[1] = *(const bh8*)(qp + 32);
  }
  fv4 oaccA[4] = {}, oaccB[4] = {};
  fv4 lA = {}, lB = {};                // row-sums, C-layout (row = 4g+r)
  float mA = -1e30f, mB = -1e30f;
  const int nktB = nq - ia;

  auto stage = [&](int buf, int j0) {
#pragma unroll
    for (int i = 0; i < 2; ++i) {
      int c = wid * 2 + i;
      int row = c * 8 + rr;
      GLD16(kb + (size_t)(j0 + row) * 64 + b8s * 8, &Ks[buf][c * 512]);
      GLD16(vb + (size_t)row * S + j0 + b8s * 8, &Vs[buf][c * 512]);
    }
  };
  stage(0, 0);

  auto process = [&](const bh8 (&kf)[2][4], const bh8 (&vf)[2][4], int j0,
                     int q0x, bh8* qf, fv4* oacc, float& mrow, fv4& lrowC) {
    const int q_my = q0x + wid * 16 + l15;
    fv4 st[4] = {};
    __builtin_amdgcn_s_setprio(1);
#pragma unroll
    for (int ks = 0; ks < 2; ++ks)
#pragma unroll
      for (int jt = 0; jt < 4; ++jt)
        st[jt] = mfma16(kf[ks][jt], qf[ks], st[jt]);
    __builtin_amdgcn_s_setprio(0);

    // mask + max on RAW scores (SC > 0 so max commutes with the scale)
    float sr[4][4];
    float mloc = -1e30f;
    const int jb = j0 + 4 * g;
    if (j0 + 63 > q0x + wid * 16) {   // diagonal tile
#pragma unroll
      for (int jt = 0; jt < 4; ++jt)
#pragma unroll
        for (int r = 0; r < 4; ++r) {
          int j = jb + jt * 16 + r;
          float s = (j <= q_my) ? st[jt][r] : -1e30f;
          sr[jt][r] = s;
          mloc = fmaxf(mloc, s);
        }
    } else {                          // interior: fully visible
#pragma unroll
      for (int jt = 0; jt < 4; ++jt)
#pragma unroll
        for (int r = 0; r < 4; ++r) {
          sr[jt][r] = st[jt][r];
          mloc = fmaxf(mloc, st[jt][r]);
        }
    }
    mloc = fmaxf(mloc, __shfl_xor(mloc, 16));
    mloc = fmaxf(mloc, __shfl_xor(mloc, 32));
    mloc *= SC;                        // scaled row max (log2 domain)
    bool defer = __all(mloc <= mrow + 8.f);   // T13
    if (!defer) {
      float mnew = fmaxf(mrow, mloc);
      float sfac = exp2f(mrow - mnew);
      mrow = mnew;
      float sfC[4];
#pragma unroll
      for (int r = 0; r < 4; ++r) sfC[r] = __shfl(sfac, g * 4 + r);
#pragma unroll
      for (int dt = 0; dt < 4; ++dt)
#pragma unroll
        for (int r = 0; r < 4; ++r) oacc[dt][r] *= sfC[r];
#pragma unroll
      for (int r = 0; r < 4; ++r) lrowC[r] *= sfC[r];
    }
    float p[4][4];
#pragma unroll
    for (int jt = 0; jt < 4; ++jt)
#pragma unroll
      for (int r = 0; r < 4; ++r)
        p[jt][r] = exp2f(fmaf(sr[jt][r], SC, -mrow));

    // PV + row-sum via MFMA (pa slot (g,i) <-> logical j matching permuted V)
    __builtin_amdgcn_s_setprio(1);
    fv4 racc = {};
#pragma unroll
    for (int ks = 0; ks < 2; ++ks) {
      uv4 w;
      w[0] = cvtpk(p[ks][0], p[ks][1]);
      w[1] = cvtpk(p[ks][2], p[ks][3]);
      w[2] = cvtpk(p[ks + 2][0], p[ks + 2][1]);
      w[3] = cvtpk(p[ks + 2][2], p[ks + 2][3]);
      bh8 pa = __builtin_bit_cast(bh8, w);
      racc = mfma16(pa, ONES, racc);
#pragma unroll
      for (int dt = 0; dt < 4; ++dt)
        oacc[dt] = mfma16(pa, vf[ks][dt], oacc[dt]);
    }
    __builtin_amdgcn_s_setprio(0);
#pragma unroll
    for (int r = 0; r < 4; ++r) lrowC[r] += racc[r];
  };

  for (int kt = 0; kt < nktB; ++kt) {
    const int j0 = kt * 64;
    __syncthreads();
    if (kt + 1 < nktB) stage((kt + 1) & 1, (kt + 1) * 64);
    const u16* Kc = Ks[kt & 1];
    const u16* Vc = Vs[kt & 1];
    bh8 kf[2][4], vf[2][4];
#pragma unroll
    for (int ks = 0; ks < 2; ++ks) {
      int b8 = ks * 4 + g;
#pragma unroll
      for (int jt = 0; jt < 4; ++jt)
        kf[ks][jt] = lds_frag(Kc, jt * 16 + l15, b8);
#pragma unroll
      for (int dt = 0; dt < 4; ++dt)
        vf[ks][dt] = lds_frag(Vc, dt * 16 + l15, b8);
    }
    process(kf, vf, j0, qb0, qfB, oaccB, mB, lB);
    if (kt <= ia) process(kf, vf, j0, qa0, qfA, oaccA, mA, lA);
  }

  auto wout = [&](fv4* oacc, fv4 lrowC, int q0x) {
#pragma unroll
    for (int dt = 0; dt < 4; ++dt)
#pragma unroll
      for (int r = 0; r < 4; ++r) {
        int row = q0x + wid * 16 + g * 4 + r;
        int col = dt * 16 + l15;
        ob[((size_t)b * S + row) * 1024 + h * 64 + col] =
            f2b(oacc[dt][r] / lrowC[r]);
      }
  };
  wout(oaccA, lA, qa0);
  wout(oaccB, lB, qb0);
}

// ---------------------------------------------------------------------------
// Gate + fused ffn-rmsnorm: computes top-2 AND writes hf_b = bf16(rmsnorm).
// ---------------------------------------------------------------------------
__global__ __launch_bounds__(256) void gate_topk(
    const float* __restrict__ x2, const float* __restrict__ nw,
    const float* __restrict__ gw, const float* __restrict__ gb,
    int* __restrict__ topk_e, float* __restrict__ topk_w,
    u16* __restrict__ hf) {
  int t = blockIdx.x * 4 + (threadIdx.x >> 6);
  int lane = threadIdx.x & 63;
  const float* xr = x2 + (size_t)t * 1024;
  float hv[16];
  float ss = 0.f;
#pragma unroll
  for (int i = 0; i < 4; ++i) {
    fv4 v = *(const fv4*)(xr + lane * 16 + i * 4);
#pragma unroll
    for (int j = 0; j < 4; ++j) {
      hv[i * 4 + j] = v[j];
      ss += v[j] * v[j];
    }
  }
#pragma unroll
  for (int off = 1; off < 64; off <<= 1) ss += __shfl_xor(ss, off);
  float inv = rsqrtf(ss * (1.0f / 1024.f) + 1e-6f);
  const fv4* nwp = (const fv4*)(nw + lane * 16);
#pragma unroll
  for (int i = 0; i < 4; ++i) {
    fv4 wv = nwp[i];
#pragma unroll
    for (int j = 0; j < 4; ++j) hv[i * 4 + j] *= inv * wv[j];
  }
  {  // fused rmsnorm output
    bh8 o0, o1;
#pragma unroll
    for (int j = 0; j < 8; ++j) {
      o0[j] = (short)f2b(hv[j]);
      o1[j] = (short)f2b(hv[8 + j]);
    }
    u16* hp = hf + (size_t)t * 1024 + lane * 16;
    *(bh8*)hp = o0;
    *(bh8*)(hp + 8) = o1;
  }
  float logit[8];
#pragma unroll
  for (int e = 0; e < 8; ++e) {
    const fv4* wp = (const fv4*)(gw + (size_t)e * 1024 + lane * 16);
    float s = 0.f;
#pragma unroll
    for (int i = 0; i < 4; ++i) {
      fv4 wv = wp[i];
#pragma unroll
      for (int j = 0; j < 4; ++j) s += hv[i * 4 + j] * wv[j];
    }
    logit[e] = s;
  }
#pragma unroll
  for (int off = 1; off < 64; off <<= 1)
#pragma unroll
    for (int e = 0; e < 8; ++e) logit[e] += __shfl_xor(logit[e], off);
  if (lane == 0) {
#pragma unroll
    for (int e = 0; e < 8; ++e) logit[e] += gb[e];
    float mx = logit[0];
#pragma unroll
    for (int e = 1; e < 8; ++e) mx = fmaxf(mx, logit[e]);
    float pe[8], se = 0.f;
#pragma unroll
    for (int e = 0; e < 8; ++e) { pe[e] = __expf(logit[e] - mx); se += pe[e]; }
    float rs = 1.f / se;
#pragma unroll
    for (int e = 0; e < 8; ++e) pe[e] *= rs;
    int i0 = 0;
    float b0 = pe[0];
#pragma unroll
    for (int e = 1; e < 8; ++e)
      if (pe[e] > b0) { b0 = pe[e]; i0 = e; }
    int i1 = -1;
    float b1v = -1.f;
#pragma unroll
    for (int e = 0; e < 8; ++e)
      if (e != i0 && pe[e] > b1v) { b1v = pe[e]; i1 = e; }
    topk_e[2 * t] = i0;
    topk_e[2 * t + 1] = i1;
    topk_w[2 * t] = b0;
    topk_w[2 * t + 1] = b1v;
  }
}

// One block, 8 waves: wave e ballot-ranks its tokens (deterministic order),
// thread 0 builds the padded tile map, then all threads fill rowid[2T]
// (compact row index of each token's two expert outputs).
__global__ __launch_bounds__(512) void route_tokens(
    const int* __restrict__ topk_e, int* __restrict__ pos_of,
    int* __restrict__ etok, int* __restrict__ meta, int* __restrict__ rowid,
    int T2) {
  __shared__ int scnt[8], sbase[8];
  const int e = threadIdx.x >> 6;
  const int lane = threadIdx.x & 63;
  int base = 0;
  for (int i0 = 0; i0 < T2; i0 += 128) {
    iv2 te = *(const iv2*)(topk_e + i0 + lane * 2);
    unsigned long long m0 = __ballot(te[0] == e);
    unsigned long long m1 = __ballot(te[1] == e);
    unsigned long long lt = (1ull << lane) - 1;
    int pre = __popcll(m0 & lt) + __popcll(m1 & lt);
    if (te[0] == e) {
      int pos = base + pre;
      etok[e * 4096 + pos] = (i0 >> 1) + lane;
      pos_of[i0 + lane * 2] = pos;
      ++pre;
    }
    if (te[1] == e) {
      int pos = base + pre;
      etok[e * 4096 + pos] = (i0 >> 1) + lane;
      pos_of[i0 + lane * 2 + 1] = pos;
    }
    base += __popcll(m0) + __popcll(m1);
  }
  if (lane == 0) scnt[e] = base;
  __syncthreads();
  if (threadIdx.x == 0) {
    int tt = 0, rb = 0;
#pragma unroll
    for (int e2 = 0; e2 < 8; ++e2) {
      sbase[e2] = rb;
      int c = scnt[e2];
      int nt = (c + 127) >> 7;
      for (int i = 0; i < nt; ++i) {
        meta[16 + tt * 4] = e2;
        meta[17 + tt * 4] = i * 128;
        meta[18 + tt * 4] = c;
        meta[19 + tt * 4] = rb + i * 128;
        ++tt;
      }
      rb += nt * 128;
    }
    meta[0] = tt;
  }
  __syncthreads();
  for (int i = threadIdx.x; i < T2; i += 512)
    rowid[i] = sbase[topk_e[i]] + pos_of[i];
}

__global__ __launch_bounds__(256) void f2b_convert(
    const float* __restrict__ src, u16* __restrict__ dst) {
  size_t i = ((size_t)blockIdx.x * 256 + threadIdx.x) * 8;
  fv4 a = *(const fv4*)(src + i);
  fv4 b = *(const fv4*)(src + i + 4);
  bh8 o;
#pragma unroll
  for (int j = 0; j < 4; ++j) o[j] = (short)f2b(a[j]);
#pragma unroll
  for (int j = 0; j < 4; ++j) o[4 + j] = (short)f2b(b[j]);
  *(bh8*)(dst + i) = o;
}

// f32 [segs*2^seg_shift, 1024] -> bf16 interleaved per 32 rows:
// src row rl of segment e -> dst row e*2^(seg_shift+1) + (rl>>5)*64 + (rl&31)
// + 32*half.  Used to build silu-fusable gate|up weight layouts.
__global__ __launch_bounds__(256) void f2b_convert_ilv(
    const float* __restrict__ src, u16* __restrict__ dst, int half,
    int seg_shift) {
  size_t i = ((size_t)blockIdx.x * 256 + threadIdx.x) * 8;
  int r = (int)(i >> 10), col = (int)(i & 1023);
  int rl = r & ((1 << seg_shift) - 1), e = r >> seg_shift;
  int dstrow = (e << (seg_shift + 1)) + ((rl >> 5) << 6) + (rl & 31) +
               (half << 5);
  fv4 a = *(const fv4*)(src + i);
  fv4 b = *(const fv4*)(src + i + 4);
  bh8 o;
#pragma unroll
  for (int j = 0; j < 4; ++j) o[j] = (short)f2b(a[j]);
#pragma unroll
  for (int j = 0; j < 4; ++j) o[4 + j] = (short)f2b(b[j]);
  *(bh8*)(dst + (size_t)dstrow * 1024 + col) = o;
}

// ---------------------------------------------------------------------------
extern "C" void kernel_launch(void* const* d_in, const int* in_sizes, int n_in,
                              void* d_out, int out_size, void* d_ws,
                              size_t ws_size, hipStream_t stream) {
  (void)in_sizes; (void)n_in; (void)out_size; (void)ws_size;
  const int Sc = 2048, Dc = 1024, NHc = 16, Tc = 4096, SH = 2048;

  const float* x   = (const float*)d_in[0];
  const float* fc  = (const float*)d_in[1];
  const float* fs  = (const float*)d_in[2];
  const float* wq  = (const float*)d_in[4];
  const float* wk  = (const float*)d_in[5];
  const float* wv  = (const float*)d_in[6];
  const float* wo  = (const float*)d_in[7];
  const float* anw = (const float*)d_in[8];
  const float* fnw = (const float*)d_in[9];
  const float* gw  = (const float*)d_in[10];
  const float* gb  = (const float*)d_in[11];
  const float* w1  = (const float*)d_in[12];
  const float* b1  = (const float*)d_in[13];
  const float* w2  = (const float*)d_in[14];
  const float* b2  = (const float*)d_in[15];
  const float* w3  = (const float*)d_in[16];
  const float* b3  = (const float*)d_in[17];
  const float* sgw = (const float*)d_in[18];
  const float* suw = (const float*)d_in[19];
  const float* sdw = (const float*)d_in[20];
  float* out = (float*)d_out;

  char* base = (char*)d_ws;
  size_t off = 0;
  auto alloc = [&](size_t bytes) -> void* {
    void* p = base + off;
    off += (bytes + 255) & ~(size_t)255;
    return p;
  };
  // weights: wqkv+wo FIRST (their region is reused as hf_b after wo-gemm)
  u16* wqkv_b = (u16*)alloc(2ull * 3072 * 1024);     // 6.29 MB
  u16* wo_b   = (u16*)alloc(2ull * 1024 * 1024);     // 2.10 MB
  u16* sgu_b  = (u16*)alloc(2ull * 4096 * 1024);     // 8.39 MB (interleaved)
  u16* sdw_b  = (u16*)alloc(2ull * 1024 * 2048);     // 4.19 MB
  u16* w13_b  = (u16*)alloc(2ull * 8 * 2048 * 1024); // 33.6 MB (interleaved)
  u16* w2_b   = (u16*)alloc(2ull * 8 * 1024 * 1024); // 16.8 MB
  // region A: qkv_out (25.2) -> eo (18.6)
  char* regA = (char*)alloc(2ull * Tc * 4096);
  // region B: h_b/qr/kr/vt/o_b (33.6) -> a13 (18.6)
  char* regB = (char*)alloc(2ull * (size_t)MAX_TILES * 128 * 2048);
  float* x2  = (float*)alloc(4ull * Tc * Dc);        // 16.8 MB
  u16* hs_b  = (u16*)alloc(2ull * Tc * SH);          // 16.8 MB
  int* topk_e = (int*)alloc(2ull * Tc * 4);
  float* topk_w = (float*)alloc(2ull * Tc * 4);
  int* pos_of = (int*)alloc(2ull * Tc * 4);
  int* rowid = (int*)alloc(2ull * Tc * 4);
  int* etok = (int*)alloc(8ull * 4096 * 4);
  int* meta = (int*)alloc(512 * 4);

  u16* qkv_out = (u16*)regA;
  u16* eo_c    = (u16*)regA;
  u16* h_b  = (u16*)regB;
  u16* qr   = (u16*)regB;
  u16* kr   = (u16*)(regB + 2ull * Tc * Dc);
  u16* vt_  = (u16*)(regB + 4ull * Tc * Dc);
  u16* o_b  = (u16*)(regB + 6ull * Tc * Dc);
  u16* a13_c = (u16*)regB;
  u16* hf_b = wqkv_b;  // overlays wqkv+wo after attention branch done

  auto conv = [&](const float* s, u16* d, size_t n) {
    f2b_convert<<<dim3((unsigned)(n / 2048)), 256, 0, stream>>>(s, d);
  };
  conv(wq, wqkv_b, (size_t)Dc * Dc);
  conv(wk, wqkv_b + 1048576, (size_t)Dc * Dc);
  conv(wv, wqkv_b + 2097152, (size_t)Dc * Dc);
  conv(wo, wo_b, (size_t)Dc * Dc);
  conv(sdw, sdw_b, (size_t)Dc * SH);
  conv(w2, w2_b, 8ull * 1024 * 1024);
  f2b_convert_ilv<<<1024, 256, 0, stream>>>(sgw, sgu_b, 0, 11);
  f2b_convert_ilv<<<1024, 256, 0, stream>>>(suw, sgu_b, 1, 11);
  f2b_convert_ilv<<<4096, 256, 0, stream>>>(w1, w13_b, 0, 10);
  f2b_convert_ilv<<<4096, 256, 0, stream>>>(w3, w13_b, 1, 10);

  // ---- attention branch ----
  rmsnorm_bf16<<<Tc, 256, 0, stream>>>(x, anw, h_b);
  gemm_bt<0><<<dim3(3072 / 128, Tc / 128), 256, 0, stream>>>(
      h_b, wqkv_b, Tc, 3072, Dc, qkv_out, nullptr, nullptr, nullptr, nullptr,
      nullptr, nullptr);
  rope_repack<<<dim3(Sc / 64, 2, 4), 256, 0, stream>>>(qkv_out, fc, fs, qr, kr,
                                                       vt_, Sc);
  attn_fwd<<<dim3(2 * NHc, Sc / 128), 256, 0, stream>>>(qr, kr, vt_, o_b, Sc,
                                                        NHc);
  gemm_bt<1, 64><<<dim3(Dc / 128, Tc / 64), 256, 0, stream>>>(
      o_b, wo_b, Tc, Dc, Dc, nullptr, x2, x, nullptr, nullptr, nullptr,
      nullptr);

  // ---- ffn branch ----
  gate_topk<<<Tc / 4, 256, 0, stream>>>(x2, fnw, gw, gb, topk_e, topk_w,
                                        hf_b);
  route_tokens<<<1, 512, 0, stream>>>(topk_e, pos_of, etok, meta, rowid,
                                      2 * Tc);

  // shared expert: fused gate|up GEMM with silu epilogue -> hs
  gemm_bt<7><<<dim3(4096 / 128, Tc / 128), 256, 0, stream>>>(
      hf_b, sgu_b, Tc, 4096, Dc, hs_b, nullptr, nullptr, nullptr, nullptr,
      nullptr, nullptr);

  // sparse MoE: gather w13 GEMM with fused silu+biases -> compact a13, w2
  gemm_bt<8><<<dim3(2048 / 128, MAX_TILES), 256, 0, stream>>>(
      hf_b, w13_b, Tc, 2048, Dc, a13_c, nullptr, b1, b3, nullptr, meta, etok);
  gemm_bt<6><<<dim3(Dc / 128, MAX_TILES), 256, 0, stream>>>(
      a13_c, w2_b, /*lda=*/1024, Dc, 1024, eo_c, nullptr, nullptr, nullptr,
      b2, meta, etok);

  // final: out = x2 + hs @ sdw^T + w0*eo[r0] + w1*eo[r1]
  gemm_bt<9, 64><<<dim3(Dc / 128, Tc / 64), 256, 0, stream>>>(
      hs_b, sdw_b, Tc, Dc, SH, eo_c, out, x2, nullptr, topk_w, rowid,
      nullptr);
}

// Round 10
// 398.228 us; speedup vs baseline: 1.1209x; 1.1209x over previous
//
#include <hip/hip_runtime.h>

// ---------------------------------------------------------------------------
// TransformerBlock on MI355X (gfx950), round 10:
//  - GEMM core reverted to round-8 (BK=64, LDS dbuf, depth-1 counted vmcnt,
//    raw barriers) -- measured best (round-9's BK=32 depth-3 regressed:
//    doubled barriers, shorter phases).
//  - sgu + w13 merged into ONE dispatch (shared gemm_body, runtime branch)
//  - w2 at TM=64 (48KB LDS -> 3 blocks/CU)
//  - everything else as round 8.
// ---------------------------------------------------------------------------

typedef unsigned short u16;
typedef __attribute__((ext_vector_type(8))) short bh8;   // 8 x bf16
typedef __attribute__((ext_vector_type(4))) float fv4;
typedef __attribute__((ext_vector_type(4))) unsigned uv4;
typedef __attribute__((ext_vector_type(2))) int iv2;

#define LOG2E 1.4426950408889634f
#define MAX_TILES 71

__device__ __forceinline__ float b2f(u16 u) {
  return __builtin_bit_cast(float, ((unsigned)u) << 16);
}
__device__ __forceinline__ u16 f2b(float f) {
  unsigned x = __builtin_bit_cast(unsigned, f);
  return (u16)((x + 0x7fffu + ((x >> 16) & 1u)) >> 16);  // RNE
}
__device__ __forceinline__ fv4 mfma16(bh8 a, bh8 b, fv4 c) {
  return __builtin_amdgcn_mfma_f32_16x16x32_bf16(a, b, c, 0, 0, 0);
}
__device__ __forceinline__ unsigned cvtpk(float lo, float hi) {
  unsigned r;
  asm("v_cvt_pk_bf16_f32 %0, %1, %2" : "=v"(r) : "v"(lo), "v"(hi));
  return r;
}

// Bijective XCD-chunk swizzle (m204).
__device__ __forceinline__ void xcd_swizzle(int& bx, int& by) {
  int gx = gridDim.x;
  int nwg = gx * gridDim.y;
  int flat = by * gx + bx;
  int q = nwg >> 3, r = nwg & 7;
  int xcd = flat & 7, idx = flat >> 3;
  int swz = (xcd < r ? xcd * (q + 1) : r * (q + 1) + (xcd - r) * q) + idx;
  by = swz / gx;
  bx = swz - by * gx;
}
__device__ __forceinline__ int xcd_swizzle1d(int flat, int nwg) {
  int q = nwg >> 3, r = nwg & 7;
  int xcd = flat & 7, idx = flat >> 3;
  return (xcd < r ? xcd * (q + 1) : r * (q + 1) + (xcd - r) * q) + idx;
}

#define GLD16(g, l)                                                        \
  __builtin_amdgcn_global_load_lds(                                        \
      (const __attribute__((address_space(1))) void*)(g),                  \
      (__attribute__((address_space(3))) void*)(l), 16, 0, 0)

// Read one MFMA fragment (16B) from a [rows][64] bf16 LDS tile whose rows are
// 128B and whose 16B blocks are XOR-swizzled by (row&7).
__device__ __forceinline__ bh8 lds_frag(const u16* base, int row, int b8) {
  int off = row * 128 + ((b8 * 16) ^ ((row & 7) << 4));
  return *(const bh8*)((const char*)base + off);
}

// ---------------------------------------------------------------------------
// Shared GEMM body: C[M,N] = A[M,K] (bf16) @ B[N,K]^T (bf16), f32 accumulate.
// TM: A-tile rows (128 or 64). B-tile is always 128 cols.
// MODE 0: Cb = bf16(gemm)
// MODE 1: Cf = add1 + gemm
// MODE 6: compact-A grouped MoE (w2): lda via M; Cb = bf16(gemm + bias_e)
//         (TM=64: by encodes tile*2+half)
// MODE 7: interleaved silu (shared expert): Cb[.,N/2] = silu(g)*u
// MODE 8: gather-A grouped MoE w13, interleaved silu + biases
// MODE 9: final: Cf = add1 + gemm + w0*eo[r0] + w1*eo[r1]
// K-loop (round-8): BK=64, dbuf, depth-1 prefetch, counted vmcnt, raw barriers.
// ---------------------------------------------------------------------------
template <int MODE, int TM>
__device__ __forceinline__ void gemm_body(
    u16* AsB, u16* BsB, int bx, int by, const u16* __restrict__ A,
    const u16* __restrict__ B, int M, int N, int K, u16* __restrict__ Cb,
    float* __restrict__ Cf, const float* __restrict__ add1,
    const float* __restrict__ add2, const float* __restrict__ bias,
    const int* __restrict__ tmeta, const int* __restrict__ etok) {
  constexpr int MR = TM / 32;  // M-frags per wave: 128->4, 64->2
  const int lane = threadIdx.x & 63;
  const int wid = threadIdx.x >> 6;
  const int wr = wid >> 1, wc = wid & 1;
  const int n0 = bx * 128;
  const int rr = lane >> 3;
  const int b8s = (lane & 7) ^ rr;
  const int ldA = (MODE == 6) ? M : K;

  int m0 = 0, e = 0, m0l = 0, cnt = 0, row0 = 0;
  const u16* Bp = B;
  if constexpr (MODE == 6 || MODE == 8) {
    int tile = by, half = 0;
    if constexpr (MODE == 6 && TM == 64) {
      tile = by >> 1;
      half = by & 1;
    }
    if (tile >= tmeta[0]) return;
    e = tmeta[16 + tile * 4];
    m0l = tmeta[17 + tile * 4];
    cnt = tmeta[18 + tile * 4];
    row0 = tmeta[19 + tile * 4] + half * 64;
    Bp = B + (size_t)e * N * K;
  } else {
    m0 = by * TM;
  }

  const u16* Arow[MR];
  const u16* Brow[4];
#pragma unroll
  for (int i = 0; i < MR; ++i) {
    int c = wid * MR + i;
    int row = c * 8 + rr;
    if constexpr (MODE == 8) {
      int li = m0l + row;
      li = li < cnt ? li : cnt - 1;
      int tok = etok[e * 4096 + li];
      Arow[i] = A + (size_t)tok * ldA + b8s * 8;
    } else if constexpr (MODE == 6) {
      Arow[i] = A + (size_t)(row0 + row) * ldA + b8s * 8;
    } else {
      Arow[i] = A + (size_t)(m0 + row) * ldA + b8s * 8;
    }
  }
#pragma unroll
  for (int i = 0; i < 4; ++i)
    Brow[i] = Bp + (size_t)(n0 + (wid * 4 + i) * 8 + rr) * K + b8s * 8;

  fv4 acc[MR][4] = {};
  const int nt = K >> 6;

  // prologue: stage tile 0 into buffer 0
#pragma unroll
  for (int i = 0; i < MR; ++i)
    GLD16(Arow[i], &AsB[(wid * MR + i) * 512]);
#pragma unroll
  for (int i = 0; i < 4; ++i)
    GLD16(Brow[i], &BsB[(wid * 4 + i) * 512]);

  for (int t = 0; t < nt; ++t) {
    const int cur = t & 1;
    u16* Asc = AsB + cur * (TM * 64);
    u16* Bsc = BsB + cur * (128 * 64);
    if (t + 1 < nt) {
      const int k0 = (t + 1) * 64;
      u16* Asn = AsB + (cur ^ 1) * (TM * 64);
      u16* Bsn = BsB + (cur ^ 1) * (128 * 64);
#pragma unroll
      for (int i = 0; i < MR; ++i)
        GLD16(Arow[i] + k0, &Asn[(wid * MR + i) * 512]);
#pragma unroll
      for (int i = 0; i < 4; ++i)
        GLD16(Brow[i] + k0, &Bsn[(wid * 4 + i) * 512]);
      // wait only for the OLDEST (cur-tile) loads; next-tile stays in flight
      if constexpr (MR == 4)
        asm volatile("s_waitcnt vmcnt(8)" ::: "memory");
      else
        asm volatile("s_waitcnt vmcnt(6)" ::: "memory");
    } else {
      asm volatile("s_waitcnt vmcnt(0)" ::: "memory");
    }
    __builtin_amdgcn_s_barrier();          // buf[cur] visible to all waves
    __builtin_amdgcn_sched_barrier(0);     // pin ds_reads below barrier

#pragma unroll
    for (int ks = 0; ks < 2; ++ks) {
      int b8 = ks * 4 + (lane >> 4);
      bh8 af[MR], bf[4];
#pragma unroll
      for (int mi = 0; mi < MR; ++mi)
        af[mi] = lds_frag(Asc, wr * (16 * MR) + mi * 16 + (lane & 15), b8);
#pragma unroll
      for (int ni = 0; ni < 4; ++ni)
        bf[ni] = lds_frag(Bsc, wc * 64 + ni * 16 + (lane & 15), b8);
      __builtin_amdgcn_s_setprio(1);
#pragma unroll
      for (int mi = 0; mi < MR; ++mi)
#pragma unroll
        for (int ni = 0; ni < 4; ++ni)
          acc[mi][ni] = mfma16(af[mi], bf[ni], acc[mi][ni]);
      __builtin_amdgcn_s_setprio(0);
    }
    __builtin_amdgcn_sched_barrier(0);     // pin reads above barrier
    __builtin_amdgcn_s_barrier();          // all waves done reading buf[cur]
    __builtin_amdgcn_sched_barrier(0);     // pin next stage below barrier
  }

  const int rbase = (MODE == 6 || MODE == 8) ? row0 : m0;
  const int r0b = rbase + wr * (16 * MR) + (lane >> 4) * 4;
  const int c0b = n0 + wc * 64 + (lane & 15);

  if constexpr (MODE == 7 || MODE == 8) {
    const int OUTN = N >> 1;
    const int colb = (n0 >> 1) + wc * 32;
    const float* bb1 = nullptr;
    const float* bb3 = nullptr;
    if constexpr (MODE == 8) {
      bb1 = add1 + (size_t)e * OUTN;
      bb3 = add2 + (size_t)e * OUTN;
    }
#pragma unroll
    for (int mi = 0; mi < MR; ++mi) {
#pragma unroll
      for (int ni = 0; ni < 2; ++ni) {
        int c = colb + ni * 16 + (lane & 15);
#pragma unroll
        for (int r = 0; r < 4; ++r) {
          int row = r0b + mi * 16 + r;
          float xg = acc[mi][ni][r];
          float yu = acc[mi][ni + 2][r];
          if constexpr (MODE == 8) {
            xg += bb1[c];
            yu += bb3[c];
          }
          float s = xg / (1.f + __expf(-xg));
          Cb[(size_t)row * OUTN + c] = f2b(s * yu);
        }
      }
    }
  } else if constexpr (MODE == 9) {
#pragma unroll
    for (int mi = 0; mi < MR; ++mi) {
#pragma unroll
      for (int r = 0; r < 4; ++r) {
        int row = r0b + mi * 16 + r;
        int g0 = tmeta[2 * row], g1 = tmeta[2 * row + 1];
        float w0 = bias[2 * row], w1 = bias[2 * row + 1];
        const u16* e0p = Cb + (size_t)g0 * 1024;
        const u16* e1p = Cb + (size_t)g1 * 1024;
#pragma unroll
        for (int ni = 0; ni < 4; ++ni) {
          int c = c0b + ni * 16;
          size_t idx = (size_t)row * N + c;
          Cf[idx] = add1[idx] + acc[mi][ni][r] + w0 * b2f(e0p[c]) +
                    w1 * b2f(e1p[c]);
        }
      }
    }
  } else {
    const float* bb = nullptr;
    if constexpr (MODE == 6) bb = bias + (size_t)e * N;
#pragma unroll
    for (int mi = 0; mi < MR; ++mi) {
#pragma unroll
      for (int ni = 0; ni < 4; ++ni) {
        int c = c0b + ni * 16;
#pragma unroll
        for (int r = 0; r < 4; ++r) {
          int row = r0b + mi * 16 + r;
          size_t idx = (size_t)row * N + c;
          float v = acc[mi][ni][r];
          if constexpr (MODE == 0) Cb[idx] = f2b(v);
          else if constexpr (MODE == 1) Cf[idx] = add1[idx] + v;
          else Cb[idx] = f2b(v + bb[c]);
        }
      }
    }
  }
}

template <int MODE, int TM = 128>
__global__ __launch_bounds__(256) void gemm_bt(
    const u16* __restrict__ A, const u16* __restrict__ B, int M, int N, int K,
    u16* __restrict__ Cb, float* __restrict__ Cf,
    const float* __restrict__ add1, const float* __restrict__ add2,
    const float* __restrict__ bias, const int* __restrict__ tmeta,
    const int* __restrict__ etok) {
  __shared__ u16 As[2][TM * 64];
  __shared__ u16 Bs[2][128 * 64];
  int bx = blockIdx.x, by = blockIdx.y;
  xcd_swizzle(bx, by);
  gemm_body<MODE, TM>(&As[0][0], &Bs[0][0], bx, by, A, B, M, N, K, Cb, Cf,
                      add1, add2, bias, tmeta, etok);
}

// Merged shared-expert (MODE 7) + MoE w13 (MODE 8) dispatch.
// Grid: 1024 sgu blocks (32x32) + 16*MAX_TILES w13 blocks, 1-D flattened.
__global__ __launch_bounds__(256) void gemm_sgu_w13(
    const u16* __restrict__ hf, const u16* __restrict__ sgu_w,
    u16* __restrict__ hs, const u16* __restrict__ w13_w,
    u16* __restrict__ a13, const float* __restrict__ b1,
    const float* __restrict__ b3, const int* __restrict__ meta,
    const int* __restrict__ etok) {
  __shared__ u16 As[2][128 * 64];
  __shared__ u16 Bs[2][128 * 64];
  const int nwg = 1024 + 16 * MAX_TILES;
  int flat = xcd_swizzle1d((int)blockIdx.x, nwg);
  if (flat < 1024) {
    int by = flat >> 5, bx = flat & 31;
    gemm_body<7, 128>(&As[0][0], &Bs[0][0], bx, by, hf, sgu_w, 4096, 4096,
                      1024, hs, nullptr, nullptr, nullptr, nullptr, nullptr,
                      nullptr);
  } else {
    int idx = flat - 1024;
    int by = idx >> 4, bx = idx & 15;
    gemm_body<8, 128>(&As[0][0], &Bs[0][0], bx, by, hf, w13_w, 4096, 2048,
                      1024, a13, nullptr, b1, b3, nullptr, meta, etok);
  }
}

// ---------------------------------------------------------------------------
// RMSNorm: f32 [T,1024] -> bf16 [T,1024], one block per token.
// ---------------------------------------------------------------------------
__global__ __launch_bounds__(256) void rmsnorm_bf16(
    const float* __restrict__ x, const float* __restrict__ w,
    u16* __restrict__ out) {
  int t = blockIdx.x;
  const float* xr = x + (size_t)t * 1024;
  fv4 v = *(const fv4*)(xr + threadIdx.x * 4);
  float ss = v[0] * v[0] + v[1] * v[1] + v[2] * v[2] + v[3] * v[3];
#pragma unroll
  for (int off = 1; off < 64; off <<= 1) ss += __shfl_xor(ss, off);
  __shared__ float red[4];
  int lane = threadIdx.x & 63, wid = threadIdx.x >> 6;
  if (lane == 0) red[wid] = ss;
  __syncthreads();
  float inv = rsqrtf((red[0] + red[1] + red[2] + red[3]) * (1.0f / 1024.f) + 1e-6f);
  u16* op = out + (size_t)t * 1024 + threadIdx.x * 4;
  const float* wp = w + threadIdx.x * 4;
#pragma unroll
  for (int i = 0; i < 4; ++i) op[i] = f2b(v[i] * inv * wp[i]);
}

// ---------------------------------------------------------------------------
// RoPE + repack from fused qkv [T,3072]:
//   q,k -> rotated [B,NH,S,64]; v -> vt [B,NH,64,S] (transposed AND column-
//   permuted per 64-block: physical group pg=4ks+g holds logical j
//   {16ks+4g+r, 16ks+32+4g+r}).  Grid: (S/64, B, NH/4).
// ---------------------------------------------------------------------------
__global__ __launch_bounds__(256) void rope_repack(
    const u16* __restrict__ qkv, const float* __restrict__ fc,
    const float* __restrict__ fs, u16* __restrict__ qr, u16* __restrict__ kr,
    u16* __restrict__ vt, int S) {
  __shared__ u16 tile[64][65];
  const int s0 = blockIdx.x * 64;
  const int b = blockIdx.y;
  const int h0 = blockIdx.z * 4;
#pragma unroll 4
  for (int it = 0; it < 32; ++it) {
    int idx = threadIdx.x + it * 256;
    int tl = idx >> 7, rem = idx & 127;
    int h = h0 + (rem >> 5), i = rem & 31;
    int s = s0 + tl;
    float c = fc[s * 32 + i], sn = fs[s * 32 + i];
    size_t src = ((size_t)(b * S + s)) * 3072 + h * 64 + 2 * i;
    size_t dst = ((size_t)((b * 16 + h) * S + s)) * 64 + 2 * i;
    float a0 = b2f(qkv[src]), a1 = b2f(qkv[src + 1]);
    qr[dst] = f2b(a0 * c - a1 * sn);
    qr[dst + 1] = f2b(a0 * sn + a1 * c);
    float b0 = b2f(qkv[src + 1024]), b1 = b2f(qkv[src + 1025]);
    kr[dst] = f2b(b0 * c - b1 * sn);
    kr[dst + 1] = f2b(b0 * sn + b1 * c);
  }
  for (int hh = 0; hh < 4; ++hh) {
    int h = h0 + hh;
    __syncthreads();
    for (int cc = threadIdx.x; cc < 512; cc += 256) {
      int tl = cc >> 3, d8 = cc & 7;
      bh8 val = *(const bh8*)(qkv + ((size_t)(b * S + s0 + tl)) * 3072 + 2048 +
                              h * 64 + d8 * 8);
#pragma unroll
      for (int j = 0; j < 8; ++j) tile[tl][d8 * 8 + j] = (u16)val[j];
    }
    __syncthreads();
    for (int cc = threadIdx.x; cc < 512; cc += 256) {
      int d = cc >> 3, pg = cc & 7;
      int sbase = 16 * (pg >> 2) + 4 * (pg & 3);
      bh8 o;
#pragma unroll
      for (int j = 0; j < 8; ++j)
        o[j] = (short)tile[sbase + (j & 3) + ((j >> 2) << 5)][d];
      *(bh8*)(vt + ((size_t)((b * 16 + h) * 64 + d)) * S + s0 + pg * 8) = o;
    }
  }
}

// ---------------------------------------------------------------------------
// Flash attention (causal), paired q-tiles, hoisted shared K/V frags,
// MFMA row-sum (l in C-layout), fma-folded scale, defer-max.
// Grid: (B*NH, nq/2). 4 waves x 16 q-rows, KVBLK=64, dbuf staging.
// ---------------------------------------------------------------------------
__global__ __launch_bounds__(256) void attn_fwd(
    const u16* __restrict__ qr, const u16* __restrict__ kr,
    const u16* __restrict__ vt, u16* __restrict__ ob, int S, int NHc) {
  __shared__ u16 Ks[2][64 * 64];
  __shared__ u16 Vs[2][64 * 64];   // V^T tile, column-permuted
  const int lane = threadIdx.x & 63;
  const int wid = threadIdx.x >> 6;
  const int g = lane >> 4;
  const int l15 = lane & 15;
  const int bh = blockIdx.x;
  const int ia = blockIdx.y;
  const int nq = S / 64;
  const int qa0 = ia * 64;                 // light q-tile
  const int qb0 = (nq - 1 - ia) * 64;      // heavy q-tile
  const int b = bh / NHc, h = bh % NHc;
  const u16* qbase = qr + (size_t)bh * S * 64;
  const u16* kb = kr + (size_t)bh * S * 64;
  const u16* vb = vt + (size_t)bh * 64 * S;
  const float SC = 0.015625f * LOG2E;  // both ref scales, log2 domain
  const int rr = lane >> 3;
  const int b8s = (lane & 7) ^ rr;

  bh8 ONES;
#pragma unroll
  for (int j = 0; j < 8; ++j) ONES[j] = (short)0x3f80;  // bf16 1.0

  bh8 qfA[2], qfB[2];
  {
    const u16* qp = qbase + (size_t)(qa0 + wid * 16 + l15) * 64 + g * 8;
    qfA[0] = *(const bh8*)qp;
    qfA[1] = *(const bh8*)(qp + 32);
    qp = qbase + (size_t)(qb0 + wid * 16 + l15) * 64 + g * 8;
    qfB[0] = *(const bh8*)qp;
    qfB[1] = *(const bh8*)(qp + 32);
  }
  fv4 oaccA[4] = {}, oaccB[4] = {};
  fv4 lA = {}, lB = {};                // row-sums, C-layout (row = 4g+r)
  float mA = -1e30f, mB = -1e30f;
  const int nktB = nq - ia;

  auto stage = [&](int buf, int j0) {
#pragma unroll
    for (int i = 0; i < 2; ++i) {
      int c = wid * 2 + i;
      int row = c * 8 + rr;
      GLD16(kb + (size_t)(j0 + row) * 64 + b8s * 8, &Ks[buf][c * 512]);
      GLD16(vb + (size_t)row * S + j0 + b8s * 8, &Vs[buf][c * 512]);
    }
  };
  stage(0, 0);

  auto process = [&](const bh8 (&kf)[2][4], const bh8 (&vf)[2][4], int j0,
                     int q0x, bh8* qf, fv4* oacc, float& mrow, fv4& lrowC) {
    const int q_my = q0x + wid * 16 + l15;
    fv4 st[4] = {};
    __builtin_amdgcn_s_setprio(1);
#pragma unroll
    for (int ks = 0; ks < 2; ++ks)
#pragma unroll
      for (int jt = 0; jt < 4; ++jt)
        st[jt] = mfma16(kf[ks][jt], qf[ks], st[jt]);
    __builtin_amdgcn_s_setprio(0);

    // mask + max on RAW scores (SC > 0 so max commutes with the scale)
    float sr[4][4];
    float mloc = -1e30f;
    const int jb = j0 + 4 * g;
    if (j0 + 63 > q0x + wid * 16) {   // diagonal tile
#pragma unroll
      for (int jt = 0; jt < 4; ++jt)
#pragma unroll
        for (int r = 0; r < 4; ++r) {
          int j = jb + jt * 16 + r;
          float s = (j <= q_my) ? st[jt][r] : -1e30f;
          sr[jt][r] = s;
          mloc = fmaxf(mloc, s);
        }
    } else {                          // interior: fully visible
#pragma unroll
      for (int jt = 0; jt < 4; ++jt)
#pragma unroll
        for (int r = 0; r < 4; ++r) {
          sr[jt][r] = st[jt][r];
          mloc = fmaxf(mloc, st[jt][r]);
        }
    }
    mloc = fmaxf(mloc, __shfl_xor(mloc, 16));
    mloc = fmaxf(mloc, __shfl_xor(mloc, 32));
    mloc *= SC;                        // scaled row max (log2 domain)
    bool defer = __all(mloc <= mrow + 8.f);   // T13
    if (!defer) {
      float mnew = fmaxf(mrow, mloc);
      float sfac = exp2f(mrow - mnew);
      mrow = mnew;
      float sfC[4];
#pragma unroll
      for (int r = 0; r < 4; ++r) sfC[r] = __shfl(sfac, g * 4 + r);
#pragma unroll
      for (int dt = 0; dt < 4; ++dt)
#pragma unroll
        for (int r = 0; r < 4; ++r) oacc[dt][r] *= sfC[r];
#pragma unroll
      for (int r = 0; r < 4; ++r) lrowC[r] *= sfC[r];
    }
    float p[4][4];
#pragma unroll
    for (int jt = 0; jt < 4; ++jt)
#pragma unroll
      for (int r = 0; r < 4; ++r)
        p[jt][r] = exp2f(fmaf(sr[jt][r], SC, -mrow));

    // PV + row-sum via MFMA (pa slot (g,i) <-> logical j matching permuted V)
    __builtin_amdgcn_s_setprio(1);
    fv4 racc = {};
#pragma unroll
    for (int ks = 0; ks < 2; ++ks) {
      uv4 w;
      w[0] = cvtpk(p[ks][0], p[ks][1]);
      w[1] = cvtpk(p[ks][2], p[ks][3]);
      w[2] = cvtpk(p[ks + 2][0], p[ks + 2][1]);
      w[3] = cvtpk(p[ks + 2][2], p[ks + 2][3]);
      bh8 pa = __builtin_bit_cast(bh8, w);
      racc = mfma16(pa, ONES, racc);
#pragma unroll
      for (int dt = 0; dt < 4; ++dt)
        oacc[dt] = mfma16(pa, vf[ks][dt], oacc[dt]);
    }
    __builtin_amdgcn_s_setprio(0);
#pragma unroll
    for (int r = 0; r < 4; ++r) lrowC[r] += racc[r];
  };

  for (int kt = 0; kt < nktB; ++kt) {
    const int j0 = kt * 64;
    __syncthreads();
    if (kt + 1 < nktB) stage((kt + 1) & 1, (kt + 1) * 64);
    const u16* Kc = Ks[kt & 1];
    const u16* Vc = Vs[kt & 1];
    bh8 kf[2][4], vf[2][4];
#pragma unroll
    for (int ks = 0; ks < 2; ++ks) {
      int b8 = ks * 4 + g;
#pragma unroll
      for (int jt = 0; jt < 4; ++jt)
        kf[ks][jt] = lds_frag(Kc, jt * 16 + l15, b8);
#pragma unroll
      for (int dt = 0; dt < 4; ++dt)
        vf[ks][dt] = lds_frag(Vc, dt * 16 + l15, b8);
    }
    process(kf, vf, j0, qb0, qfB, oaccB, mB, lB);
    if (kt <= ia) process(kf, vf, j0, qa0, qfA, oaccA, mA, lA);
  }

  auto wout = [&](fv4* oacc, fv4 lrowC, int q0x) {
#pragma unroll
    for (int dt = 0; dt < 4; ++dt)
#pragma unroll
      for (int r = 0; r < 4; ++r) {
        int row = q0x + wid * 16 + g * 4 + r;
        int col = dt * 16 + l15;
        ob[((size_t)b * S + row) * 1024 + h * 64 + col] =
            f2b(oacc[dt][r] / lrowC[r]);
      }
  };
  wout(oaccA, lA, qa0);
  wout(oaccB, lB, qb0);
}

// ---------------------------------------------------------------------------
// Gate + fused ffn-rmsnorm: computes top-2 AND writes hf_b = bf16(rmsnorm).
// ---------------------------------------------------------------------------
__global__ __launch_bounds__(256) void gate_topk(
    const float* __restrict__ x2, const float* __restrict__ nw,
    const float* __restrict__ gw, const float* __restrict__ gb,
    int* __restrict__ topk_e, float* __restrict__ topk_w,
    u16* __restrict__ hf) {
  int t = blockIdx.x * 4 + (threadIdx.x >> 6);
  int lane = threadIdx.x & 63;
  const float* xr = x2 + (size_t)t * 1024;
  float hv[16];
  float ss = 0.f;
#pragma unroll
  for (int i = 0; i < 4; ++i) {
    fv4 v = *(const fv4*)(xr + lane * 16 + i * 4);
#pragma unroll
    for (int j = 0; j < 4; ++j) {
      hv[i * 4 + j] = v[j];
      ss += v[j] * v[j];
    }
  }
#pragma unroll
  for (int off = 1; off < 64; off <<= 1) ss += __shfl_xor(ss, off);
  float inv = rsqrtf(ss * (1.0f / 1024.f) + 1e-6f);
  const fv4* nwp = (const fv4*)(nw + lane * 16);
#pragma unroll
  for (int i = 0; i < 4; ++i) {
    fv4 wv = nwp[i];
#pragma unroll
    for (int j = 0; j < 4; ++j) hv[i * 4 + j] *= inv * wv[j];
  }
  {  // fused rmsnorm output
    bh8 o0, o1;
#pragma unroll
    for (int j = 0; j < 8; ++j) {
      o0[j] = (short)f2b(hv[j]);
      o1[j] = (short)f2b(hv[8 + j]);
    }
    u16* hp = hf + (size_t)t * 1024 + lane * 16;
    *(bh8*)hp = o0;
    *(bh8*)(hp + 8) = o1;
  }
  float logit[8];
#pragma unroll
  for (int e = 0; e < 8; ++e) {
    const fv4* wp = (const fv4*)(gw + (size_t)e * 1024 + lane * 16);
    float s = 0.f;
#pragma unroll
    for (int i = 0; i < 4; ++i) {
      fv4 wv = wp[i];
#pragma unroll
      for (int j = 0; j < 4; ++j) s += hv[i * 4 + j] * wv[j];
    }
    logit[e] = s;
  }
#pragma unroll
  for (int off = 1; off < 64; off <<= 1)
#pragma unroll
    for (int e = 0; e < 8; ++e) logit[e] += __shfl_xor(logit[e], off);
  if (lane == 0) {
#pragma unroll
    for (int e = 0; e < 8; ++e) logit[e] += gb[e];
    float mx = logit[0];
#pragma unroll
    for (int e = 1; e < 8; ++e) mx = fmaxf(mx, logit[e]);
    float pe[8], se = 0.f;
#pragma unroll
    for (int e = 0; e < 8; ++e) { pe[e] = __expf(logit[e] - mx); se += pe[e]; }
    float rs = 1.f / se;
#pragma unroll
    for (int e = 0; e < 8; ++e) pe[e] *= rs;
    int i0 = 0;
    float b0 = pe[0];
#pragma unroll
    for (int e = 1; e < 8; ++e)
      if (pe[e] > b0) { b0 = pe[e]; i0 = e; }
    int i1 = -1;
    float b1v = -1.f;
#pragma unroll
    for (int e = 0; e < 8; ++e)
      if (e != i0 && pe[e] > b1v) { b1v = pe[e]; i1 = e; }
    topk_e[2 * t] = i0;
    topk_e[2 * t + 1] = i1;
    topk_w[2 * t] = b0;
    topk_w[2 * t + 1] = b1v;
  }
}

// One block, 8 waves: wave e ballot-ranks its tokens (deterministic order),
// thread 0 builds the padded tile map, then all threads fill rowid[2T]
// (compact row index of each token's two expert outputs).
__global__ __launch_bounds__(512) void route_tokens(
    const int* __restrict__ topk_e, int* __restrict__ pos_of,
    int* __restrict__ etok, int* __restrict__ meta, int* __restrict__ rowid,
    int T2) {
  __shared__ int scnt[8], sbase[8];
  const int e = threadIdx.x >> 6;
  const int lane = threadIdx.x & 63;
  int base = 0;
  for (int i0 = 0; i0 < T2; i0 += 128) {
    iv2 te = *(const iv2*)(topk_e + i0 + lane * 2);
    unsigned long long m0 = __ballot(te[0] == e);
    unsigned long long m1 = __ballot(te[1] == e);
    unsigned long long lt = (1ull << lane) - 1;
    int pre = __popcll(m0 & lt) + __popcll(m1 & lt);
    if (te[0] == e) {
      int pos = base + pre;
      etok[e * 4096 + pos] = (i0 >> 1) + lane;
      pos_of[i0 + lane * 2] = pos;
      ++pre;
    }
    if (te[1] == e) {
      int pos = base + pre;
      etok[e * 4096 + pos] = (i0 >> 1) + lane;
      pos_of[i0 + lane * 2 + 1] = pos;
    }
    base += __popcll(m0) + __popcll(m1);
  }
  if (lane == 0) scnt[e] = base;
  __syncthreads();
  if (threadIdx.x == 0) {
    int tt = 0, rb = 0;
#pragma unroll
    for (int e2 = 0; e2 < 8; ++e2) {
      sbase[e2] = rb;
      int c = scnt[e2];
      int nt = (c + 127) >> 7;
      for (int i = 0; i < nt; ++i) {
        meta[16 + tt * 4] = e2;
        meta[17 + tt * 4] = i * 128;
        meta[18 + tt * 4] = c;
        meta[19 + tt * 4] = rb + i * 128;
        ++tt;
      }
      rb += nt * 128;
    }
    meta[0] = tt;
  }
  __syncthreads();
  for (int i = threadIdx.x; i < T2; i += 512)
    rowid[i] = sbase[topk_e[i]] + pos_of[i];
}

__global__ __launch_bounds__(256) void f2b_convert(
    const float* __restrict__ src, u16* __restrict__ dst) {
  size_t i = ((size_t)blockIdx.x * 256 + threadIdx.x) * 8;
  fv4 a = *(const fv4*)(src + i);
  fv4 b = *(const fv4*)(src + i + 4);
  bh8 o;
#pragma unroll
  for (int j = 0; j < 4; ++j) o[j] = (short)f2b(a[j]);
#pragma unroll
  for (int j = 0; j < 4; ++j) o[4 + j] = (short)f2b(b[j]);
  *(bh8*)(dst + i) = o;
}

// f32 [segs*2^seg_shift, 1024] -> bf16 interleaved per 32 rows:
// src row rl of segment e -> dst row e*2^(seg_shift+1) + (rl>>5)*64 + (rl&31)
// + 32*half.  Used to build silu-fusable gate|up weight layouts.
__global__ __launch_bounds__(256) void f2b_convert_ilv(
    const float* __restrict__ src, u16* __restrict__ dst, int half,
    int seg_shift) {
  size_t i = ((size_t)blockIdx.x * 256 + threadIdx.x) * 8;
  int r = (int)(i >> 10), col = (int)(i & 1023);
  int rl = r & ((1 << seg_shift) - 1), e = r >> seg_shift;
  int dstrow = (e << (seg_shift + 1)) + ((rl >> 5) << 6) + (rl & 31) +
               (half << 5);
  fv4 a = *(const fv4*)(src + i);
  fv4 b = *(const fv4*)(src + i + 4);
  bh8 o;
#pragma unroll
  for (int j = 0; j < 4; ++j) o[j] = (short)f2b(a[j]);
#pragma unroll
  for (int j = 0; j < 4; ++j) o[4 + j] = (short)f2b(b[j]);
  *(bh8*)(dst + (size_t)dstrow * 1024 + col) = o;
}

// ---------------------------------------------------------------------------
extern "C" void kernel_launch(void* const* d_in, const int* in_sizes, int n_in,
                              void* d_out, int out_size, void* d_ws,
                              size_t ws_size, hipStream_t stream) {
  (void)in_sizes; (void)n_in; (void)out_size; (void)ws_size;
  const int Sc = 2048, Dc = 1024, NHc = 16, Tc = 4096, SH = 2048;

  const float* x   = (const float*)d_in[0];
  const float* fc  = (const float*)d_in[1];
  const float* fs  = (const float*)d_in[2];
  const float* wq  = (const float*)d_in[4];
  const float* wk  = (const float*)d_in[5];
  const float* wv  = (const float*)d_in[6];
  const float* wo  = (const float*)d_in[7];
  const float* anw = (const float*)d_in[8];
  const float* fnw = (const float*)d_in[9];
  const float* gw  = (const float*)d_in[10];
  const float* gb  = (const float*)d_in[11];
  const float* w1  = (const float*)d_in[12];
  const float* b1  = (const float*)d_in[13];
  const float* w2  = (const float*)d_in[14];
  const float* b2  = (const float*)d_in[15];
  const float* w3  = (const float*)d_in[16];
  const float* b3  = (const float*)d_in[17];
  const float* sgw = (const float*)d_in[18];
  const float* suw = (const float*)d_in[19];
  const float* sdw = (const float*)d_in[20];
  float* out = (float*)d_out;

  char* base = (char*)d_ws;
  size_t off = 0;
  auto alloc = [&](size_t bytes) -> void* {
    void* p = base + off;
    off += (bytes + 255) & ~(size_t)255;
    return p;
  };
  // weights: wqkv+wo FIRST (their region is reused as hf_b after wo-gemm)
  u16* wqkv_b = (u16*)alloc(2ull * 3072 * 1024);     // 6.29 MB
  u16* wo_b   = (u16*)alloc(2ull * 1024 * 1024);     // 2.10 MB
  u16* sgu_b  = (u16*)alloc(2ull * 4096 * 1024);     // 8.39 MB (interleaved)
  u16* sdw_b  = (u16*)alloc(2ull * 1024 * 2048);     // 4.19 MB
  u16* w13_b  = (u16*)alloc(2ull * 8 * 2048 * 1024); // 33.6 MB (interleaved)
  u16* w2_b   = (u16*)alloc(2ull * 8 * 1024 * 1024); // 16.8 MB
  // region A: qkv_out (25.2) -> eo (18.6)
  char* regA = (char*)alloc(2ull * Tc * 4096);
  // region B: h_b/qr/kr/vt/o_b (33.6) -> a13 (18.6)
  char* regB = (char*)alloc(2ull * (size_t)MAX_TILES * 128 * 2048);
  float* x2  = (float*)alloc(4ull * Tc * Dc);        // 16.8 MB
  u16* hs_b  = (u16*)alloc(2ull * Tc * SH);          // 16.8 MB
  int* topk_e = (int*)alloc(2ull * Tc * 4);
  float* topk_w = (float*)alloc(2ull * Tc * 4);
  int* pos_of = (int*)alloc(2ull * Tc * 4);
  int* rowid = (int*)alloc(2ull * Tc * 4);
  int* etok = (int*)alloc(8ull * 4096 * 4);
  int* meta = (int*)alloc(512 * 4);

  u16* qkv_out = (u16*)regA;
  u16* eo_c    = (u16*)regA;
  u16* h_b  = (u16*)regB;
  u16* qr   = (u16*)regB;
  u16* kr   = (u16*)(regB + 2ull * Tc * Dc);
  u16* vt_  = (u16*)(regB + 4ull * Tc * Dc);
  u16* o_b  = (u16*)(regB + 6ull * Tc * Dc);
  u16* a13_c = (u16*)regB;
  u16* hf_b = wqkv_b;  // overlays wqkv+wo after attention branch done

  auto conv = [&](const float* s, u16* d, size_t n) {
    f2b_convert<<<dim3((unsigned)(n / 2048)), 256, 0, stream>>>(s, d);
  };
  conv(wq, wqkv_b, (size_t)Dc * Dc);
  conv(wk, wqkv_b + 1048576, (size_t)Dc * Dc);
  conv(wv, wqkv_b + 2097152, (size_t)Dc * Dc);
  conv(wo, wo_b, (size_t)Dc * Dc);
  conv(sdw, sdw_b, (size_t)Dc * SH);
  conv(w2, w2_b, 8ull * 1024 * 1024);
  f2b_convert_ilv<<<1024, 256, 0, stream>>>(sgw, sgu_b, 0, 11);
  f2b_convert_ilv<<<1024, 256, 0, stream>>>(suw, sgu_b, 1, 11);
  f2b_convert_ilv<<<4096, 256, 0, stream>>>(w1, w13_b, 0, 10);
  f2b_convert_ilv<<<4096, 256, 0, stream>>>(w3, w13_b, 1, 10);

  // ---- attention branch ----
  rmsnorm_bf16<<<Tc, 256, 0, stream>>>(x, anw, h_b);
  gemm_bt<0><<<dim3(3072 / 128, Tc / 128), 256, 0, stream>>>(
      h_b, wqkv_b, Tc, 3072, Dc, qkv_out, nullptr, nullptr, nullptr, nullptr,
      nullptr, nullptr);
  rope_repack<<<dim3(Sc / 64, 2, 4), 256, 0, stream>>>(qkv_out, fc, fs, qr, kr,
                                                       vt_, Sc);
  attn_fwd<<<dim3(2 * NHc, Sc / 128), 256, 0, stream>>>(qr, kr, vt_, o_b, Sc,
                                                        NHc);
  gemm_bt<1, 64><<<dim3(Dc / 128, Tc / 64), 256, 0, stream>>>(
      o_b, wo_b, Tc, Dc, Dc, nullptr, x2, x, nullptr, nullptr, nullptr,
      nullptr);

  // ---- ffn branch ----
  gate_topk<<<Tc / 4, 256, 0, stream>>>(x2, fnw, gw, gb, topk_e, topk_w,
                                        hf_b);
  route_tokens<<<1, 512, 0, stream>>>(topk_e, pos_of, etok, meta, rowid,
                                      2 * Tc);

  // merged: shared-expert gate|up (silu epilogue -> hs) + MoE w13 gather
  gemm_sgu_w13<<<dim3(1024 + 16 * MAX_TILES), 256, 0, stream>>>(
      hf_b, sgu_b, hs_b, w13_b, a13_c, b1, b3, meta, etok);

  // MoE w2 (TM=64 half-tiles: 3 blocks/CU)
  gemm_bt<6, 64><<<dim3(Dc / 128, 2 * MAX_TILES), 256, 0, stream>>>(
      a13_c, w2_b, /*lda=*/1024, Dc, 1024, eo_c, nullptr, nullptr, nullptr,
      b2, meta, etok);

  // final: out = x2 + hs @ sdw^T + w0*eo[r0] + w1*eo[r1]
  gemm_bt<9, 64><<<dim3(Dc / 128, Tc / 64), 256, 0, stream>>>(
      hs_b, sdw_b, Tc, Dc, SH, eo_c, out, x2, nullptr, topk_w, rowid,
      nullptr);
}